// Round 6
// baseline (263.002 us; speedup 1.0000x reference)
//
#include <hip/hip_runtime.h>

typedef float v4f __attribute__((ext_vector_type(4)));

#define NB 8        // batch
#define NL 24       // layers
#define NR 64       // chunks
#define ND 4096     // DL
#define NFUSED 1536
#define NTF 1024
#define NPF 512
#define KP 4096     // DP

#define TKC 288     // tfeat k-chunks of 64
#define PKC 128     // pfeat parity-chunks (64 chunks x 2 parity)
#define FKC 24      // F parity-chunks (12 kchunks of 128 x 2 parity)

// workspace float offsets
#define WS_FUSED 0          // 12288
#define WS_GATE  12288      // 192                 -> 12480
#define WS_PLA   12480      // 2*24*4096 = 196608  -> 209088
#define WS_PLB   209088     // 196608              -> 405696
#define WS_CA    405696     // 262144              -> 667840
#define WS_CBT   667840     // 262144              -> 929984
#define WS_PT    929984     // 288*8*1024 = 2359296-> 3289280
#define WS_PP    3289280    // 128*8*512 = 524288  -> 3813568
// pF aliases partT (dead after K2): 24*8*4096 = 786432 each
#define WS_PFA   929984
#define WS_PFB   1716416    // ends 2502848 (inside PT region)

// =====================================================================
// K1 — fused-independent work, 448 blocks:
//   [0,288)   tfeat partials  (k-chunk 64, v4f over all 1024 cols)
//   [288,352) pfeat partials  (k-chunk 64, parity split, v4f over 512 cols)
//   [352,416) L_A / L_B       (scalar, 16 d-chunks x 2 k-halves x 2 mats)
//   [416,448) C_A / C_BT      (scalar)
// =====================================================================
__global__ __launch_bounds__(256) void k_indep(
    const float* __restrict__ As, const float* __restrict__ Bs,
    const float* __restrict__ W_ct,
    const float* __restrict__ prompt, const float* __restrict__ W_cp,
    const float* __restrict__ E_layer, const float* __restrict__ E_chunk,
    const float* __restrict__ W_A, const float* __restrict__ W_B,
    float* __restrict__ partT, float* __restrict__ partP,
    float* __restrict__ pLA, float* __restrict__ pLB,
    float* __restrict__ CA, float* __restrict__ CBT) {
  __shared__ float sm[4096];
  const int bx = blockIdx.x;
  const int tid = threadIdx.x;

  if (bx < 288) {                       // ---- tfeat partial
    const int kc = bx;
    const int kbase = kc * 64;
    // stage x[b][kk] (8x64) into LDS
    for (int i = tid; i < 512; i += 256) {
      const int b = i >> 6, kk = i & 63;
      const int k = kbase + kk;
      sm[i] = (k < 9216) ? As[b * 9216 + k] : Bs[b * 9216 + (k - 9216)];
    }
    __syncthreads();
    const int c4 = tid * 4;
    v4f acc[NB] = {};
#pragma unroll 8
    for (int kk = 0; kk < 64; ++kk) {
      const v4f w = *(const v4f*)(W_ct + (size_t)(kbase + kk) * NTF + c4);
#pragma unroll
      for (int b = 0; b < NB; ++b) acc[b] += sm[b * 64 + kk] * w;
    }
#pragma unroll
    for (int b = 0; b < NB; ++b)
      *(v4f*)(partT + (size_t)(kc * NB + b) * NTF + c4) = acc[b];
  } else if (bx < 352) {                // ---- pfeat partial
    const int kc = bx - 288;
    const int kbase = kc * 64;
    for (int i = tid; i < 512; i += 256) {
      const int b = i >> 6, kk = i & 63;
      sm[i] = prompt[b * KP + kbase + kk];
    }
    __syncthreads();
    const int p = tid >> 7;             // row parity
    const int c4 = (tid & 127) * 4;
    v4f acc[NB] = {};
#pragma unroll 8
    for (int i = 0; i < 32; ++i) {
      const int rr = 2 * i + p;
      const v4f w = *(const v4f*)(W_cp + (size_t)(kbase + rr) * NPF + c4);
#pragma unroll
      for (int b = 0; b < NB; ++b) acc[b] += sm[b * 64 + rr] * w;
    }
#pragma unroll
    for (int b = 0; b < NB; ++b)
      *(v4f*)(partP + (size_t)((kc * 2 + p) * NB + b) * NPF + c4) = acc[b];
  } else if (bx < 416) {                // ---- L_A / L_B
    const int t = bx - 352;
    const bool isA = t < 32;
    const int tt = isA ? t : t - 32;
    const int dc = tt & 15;
    const int kh = tt >> 4;
    const float* W = (isA ? W_A : W_B) + (size_t)(NFUSED + kh * 128) * ND;
    float* pL = (isA ? pLA : pLB) + (size_t)kh * NL * ND;
    const int d = dc * 256 + tid;
    float acc[NL] = {};
    for (int kk = 0; kk < 128; ++kk) {
      const float w = W[(size_t)kk * ND + d];
      const float* el = E_layer + kh * 128 + kk;
#pragma unroll
      for (int l = 0; l < NL; ++l) acc[l] = fmaf(el[l * 256], w, acc[l]);
    }
#pragma unroll
    for (int l = 0; l < NL; ++l) pL[(size_t)l * ND + d] = acc[l];
  } else {                              // ---- C_A / C_BT
    const int t = bx - 416;
    const bool isA = t < 16;
    const int tt = isA ? t : t - 16;
    const float* W = (isA ? W_A : W_B) + (size_t)(NFUSED + 256) * ND;
    for (int i = tid; i < NR * 64; i += 256) sm[i] = E_chunk[i];
    __syncthreads();
    const int d = tt * 256 + tid;
    float w[64];
#pragma unroll
    for (int k = 0; k < 64; ++k) w[k] = W[(size_t)k * ND + d];
    for (int r = 0; r < NR; ++r) {
      float s = 0.f;
#pragma unroll
      for (int k = 0; k < 64; ++k) s = fmaf(sm[r * 64 + k], w[k], s);
      if (isA) CA[(size_t)r * ND + d] = s;
      else     CBT[(size_t)d * NR + r] = s;
    }
  }
}

// =====================================================================
// K2 — fused reduce, 384 blocks (8 k-slice threads per output + LDS)
//   [0,256)   tfeat: block = (b, jgroup of 32)
//   [256,384) pfeat: block = (b, jgroup of 32)
// =====================================================================
__global__ __launch_bounds__(256) void k_fused_reduce(
    const float* __restrict__ partT, const float* __restrict__ partP,
    const float* __restrict__ b_ct, const float* __restrict__ b_cp,
    float* __restrict__ fused) {
  __shared__ float red[256];
  const int bx = blockIdx.x;
  const int tid = threadIdx.x;
  const int ks = tid >> 5, jl = tid & 31;
  if (bx < 256) {
    const int b = bx >> 5, jg = bx & 31;
    const int j = jg * 32 + jl;
    float s = 0.f;
#pragma unroll 4
    for (int t = 0; t < 36; ++t) {
      const int kc = ks + 8 * t;
      s += partT[(size_t)(kc * NB + b) * NTF + j];
    }
    red[tid] = s;
    __syncthreads();
    if (tid < 32) {
      float tot = b_ct[j];
#pragma unroll
      for (int k = 0; k < 8; ++k) tot += red[k * 32 + tid];
      fused[b * NFUSED + j] = fmaxf(tot, 0.f);
    }
  } else {
    const int t0 = bx - 256;
    const int b = t0 >> 4, jg = t0 & 15;
    const int j = jg * 32 + jl;
    float s = 0.f;
#pragma unroll 4
    for (int t = 0; t < 16; ++t) {
      const int kc = ks + 8 * t;
      s += partP[(size_t)(kc * NB + b) * NPF + j];
    }
    red[tid] = s;
    __syncthreads();
    if (tid < 32) {
      float tot = b_cp[j];
#pragma unroll
      for (int k = 0; k < 8; ++k) tot += red[k * 32 + tid];
      fused[b * NFUSED + NTF + j] = fmaxf(tot, 0.f);
    }
  }
}

// =====================================================================
// K3 — F partials (v4f, parity split) + gate, 200 blocks
//   [0,192)  F: mat = bx>=96; t=bx%96: cg = t&7 (512 cols), kc = t>>3 (of 12)
//   [192,200) gate, one batch per block
// =====================================================================
__global__ __launch_bounds__(256) void k_dep(
    const float* __restrict__ fused,
    const float* __restrict__ W_A, const float* __restrict__ W_B,
    const float* __restrict__ W_pc, const float* __restrict__ b_pc,
    float* __restrict__ pFA, float* __restrict__ pFB,
    float* __restrict__ gate_ws, float* __restrict__ gate_out) {
  __shared__ float sm[1664];
  const int bx = blockIdx.x;
  const int tid = threadIdx.x;

  if (bx < 192) {                       // ---- F partial
    const bool isB = bx >= 96;
    const int t = isB ? bx - 96 : bx;
    const float* W = isB ? W_B : W_A;
    float* pF = isB ? pFB : pFA;
    const int cg = t & 7;
    const int kc = t >> 3;
    const int kbase = kc * 128;
    for (int i = tid; i < 1024; i += 256) {
      const int b = i >> 7, kk = i & 127;
      sm[i] = fused[b * NFUSED + kbase + kk];
    }
    __syncthreads();
    const int p = tid >> 7;
    const int c4 = cg * 512 + (tid & 127) * 4;
    v4f acc[NB] = {};
#pragma unroll 8
    for (int i = 0; i < 64; ++i) {
      const int rr = 2 * i + p;
      const v4f w = *(const v4f*)(W + (size_t)(kbase + rr) * ND + c4);
#pragma unroll
      for (int b = 0; b < NB; ++b) acc[b] += sm[b * 128 + rr] * w;
    }
#pragma unroll
    for (int b = 0; b < NB; ++b)
      *(v4f*)(pF + (size_t)((kc * 2 + p) * NB + b) * ND + c4) = acc[b];
  } else {                              // ---- gate for batch b
    const int b = bx - 192;
    for (int j = tid; j < NFUSED; j += 256) sm[j] = fused[b * NFUSED + j];
    __syncthreads();
    float acc[NL] = {};
    for (int j = tid; j < NFUSED; j += 256) {
      const float f = sm[j];
#pragma unroll
      for (int l = 0; l < NL; ++l) acc[l] = fmaf(f, W_pc[j * NL + l], acc[l]);
    }
#pragma unroll
    for (int off = 32; off > 0; off >>= 1)
#pragma unroll
      for (int l = 0; l < NL; ++l) acc[l] += __shfl_down(acc[l], off);
    const int wave = tid >> 6, lane = tid & 63;
    if (lane == 0)
#pragma unroll
      for (int l = 0; l < NL; ++l) sm[NFUSED + wave * NL + l] = acc[l];
    __syncthreads();
    if (tid < NL) {
      float s = b_pc[tid];
#pragma unroll
      for (int w = 0; w < 4; ++w) s += sm[NFUSED + w * NL + tid];
      const float g = s > 0.f ? 1.f : 0.f;
      gate_ws[b * NL + tid] = g;
      gate_out[b * NL + tid] = g;
    }
  }
}

// =====================================================================
// K4 — writers, 2304 blocks
//   [0,768)    A: bl = bx>>2, dgroup = bx&3 (1024 d), all 64 r
//   [768,2304) B: bl = t>>3, dgroup = t&7 (512 d)
// =====================================================================
__global__ __launch_bounds__(256) void k_out(
    const float* __restrict__ pFA, const float* __restrict__ pFB,
    const float* __restrict__ b_A, const float* __restrict__ b_B,
    const float* __restrict__ pLA, const float* __restrict__ pLB,
    const float* __restrict__ CA, const float* __restrict__ CBT,
    const float* __restrict__ gate,
    float* __restrict__ outA, float* __restrict__ outB) {
  __shared__ float sbase[512];
  const int bx = blockIdx.x;
  const int tid = threadIdx.x;
  if (bx < 768) {                       // ---- A writer
    const int bl = bx >> 2;
    const int dg = bx & 3;
    const int b = bl / NL, l = bl % NL;
    const int d = dg * 1024 + tid * 4;
    const float g = gate[bl];
    v4f base = *(const v4f*)(b_A + d);
#pragma unroll
    for (int kc = 0; kc < FKC; ++kc)
      base += *(const v4f*)(pFA + (size_t)(kc * NB + b) * ND + d);
    base += *(const v4f*)(pLA + (size_t)l * ND + d);
    base += *(const v4f*)(pLA + (size_t)(NL + l) * ND + d);
    float* outp = outA + (size_t)bl * NR * ND + d;
#pragma unroll 4
    for (int r = 0; r < NR; ++r) {
      const v4f c = *(const v4f*)(CA + (size_t)r * ND + d);
      const v4f v = (base + c) * g;
      __builtin_nontemporal_store(v, (v4f*)(outp + (size_t)r * ND));
    }
  } else {                              // ---- B writer
    const int t = bx - 768;
    const int bl = t >> 3;
    const int b = bl / NL, l = bl % NL;
    const int dbase = (t & 7) * 512;
    for (int dd = tid; dd < 512; dd += 256) {
      const int d = dbase + dd;
      float s = b_B[d] + pLB[(size_t)l * ND + d] + pLB[(size_t)(NL + l) * ND + d];
#pragma unroll
      for (int kc = 0; kc < FKC; ++kc)
        s += pFB[(size_t)(kc * NB + b) * ND + d];
      sbase[dd] = s;
    }
    __syncthreads();
    const int dloc0 = tid >> 2;
    const int r0 = (tid & 3) * 16;
#pragma unroll 2
    for (int i = 0; i < 8; ++i) {
      const int dloc = i * 64 + dloc0;
      const int d = dbase + dloc;
      const float base = sbase[dloc];
#pragma unroll
      for (int q = 0; q < 4; ++q) {
        const v4f c = *(const v4f*)(CBT + (size_t)d * NR + r0 + q * 4);
        const v4f v = c + base;
        __builtin_nontemporal_store(v, (v4f*)(outB + ((size_t)bl * ND + d) * NR + r0 + q * 4));
      }
    }
  }
}

extern "C" void kernel_launch(void* const* d_in, const int* in_sizes, int n_in,
                              void* d_out, int out_size, void* d_ws, size_t ws_size,
                              hipStream_t stream) {
  const float* A_small   = (const float*)d_in[0];
  const float* B_small   = (const float*)d_in[1];
  const float* prompt    = (const float*)d_in[2];
  const float* W_ct      = (const float*)d_in[3];
  const float* b_ct      = (const float*)d_in[4];
  const float* W_cp      = (const float*)d_in[5];
  const float* b_cp      = (const float*)d_in[6];
  const float* W_pc      = (const float*)d_in[7];
  const float* b_pc      = (const float*)d_in[8];
  const float* E_layer   = (const float*)d_in[9];
  const float* E_chunk   = (const float*)d_in[10];
  const float* W_A       = (const float*)d_in[11];
  const float* b_A       = (const float*)d_in[12];
  const float* W_B       = (const float*)d_in[13];
  const float* b_B       = (const float*)d_in[14];

  float* ws    = (float*)d_ws;
  float* fused = ws + WS_FUSED;
  float* gatew = ws + WS_GATE;
  float* pLA   = ws + WS_PLA;
  float* pLB   = ws + WS_PLB;
  float* CA    = ws + WS_CA;
  float* CBT   = ws + WS_CBT;
  float* partT = ws + WS_PT;
  float* partP = ws + WS_PP;
  float* pFA   = ws + WS_PFA;   // aliases partT region (dead after K2)
  float* pFB   = ws + WS_PFB;

  float* outA = (float*)d_out;                       // [192,64,4096]
  float* outB = outA + (size_t)192 * NR * ND;        // [192,4096,64]
  float* outG = outB + (size_t)192 * ND * NR;        // [192]

  k_indep<<<448, 256, 0, stream>>>(A_small, B_small, W_ct, prompt, W_cp,
                                   E_layer, E_chunk, W_A, W_B,
                                   partT, partP, pLA, pLB, CA, CBT);
  k_fused_reduce<<<384, 256, 0, stream>>>(partT, partP, b_ct, b_cp, fused);
  k_dep<<<200, 256, 0, stream>>>(fused, W_A, W_B, W_pc, b_pc,
                                 pFA, pFB, gatew, outG);
  k_out<<<2304, 256, 0, stream>>>(pFA, pFB, b_A, b_B, pLA, pLB, CA, CBT,
                                  gatew, outA, outB);
}

// Round 7
// 142.787 us; speedup vs baseline: 1.8419x; 1.8419x over previous
//
#include <hip/hip_runtime.h>

typedef float v4f __attribute__((ext_vector_type(4)));

#define NB 8        // batch
#define NL 24       // layers
#define NR 64       // chunks
#define ND 4096     // DL
#define NFUSED 1536
#define NTF 1024
#define NPF 512
#define KP 4096     // DP

#define FKC 12      // F k-chunks of 128

// workspace float offsets
#define WS_FACC  0          // 4*8*1536 = 49152
#define WS_GATE  49152      // 192               -> 49344
#define WS_PLA   49344      // 2*24*4096=196608  -> 245952
#define WS_PLB   245952     // 196608            -> 442560
#define WS_CA    442560     // 262144            -> 704704
#define WS_CBT   704704     // 262144            -> 966848
#define WS_PFA   966848     // 12*8*4096=393216  -> 1360064
#define WS_PFB   1360064    // 393216            -> 1753280

// =====================================================================
// K1: everything independent of `fused` — 736 blocks (R3 structure).
//   [0,576)   tfeat partials -> atomicAdd into fAcc[kc&3][b][j]
//   [576,640) pfeat partials -> atomicAdd into fAcc[kc&3][b][1024+j]
//   [640,704) L_A / L_B      (16 d-chunks x 2 k-halves x 2 mats)
//   [704,736) C_A / C_BT     (16 d-chunks x 2 mats)
// =====================================================================
__global__ __launch_bounds__(256) void k_indep(
    const float* __restrict__ As, const float* __restrict__ Bs,
    const float* __restrict__ W_ct,
    const float* __restrict__ prompt, const float* __restrict__ W_cp,
    const float* __restrict__ E_layer, const float* __restrict__ E_chunk,
    const float* __restrict__ W_A, const float* __restrict__ W_B,
    float* __restrict__ fAcc,
    float* __restrict__ pLA, float* __restrict__ pLB,
    float* __restrict__ CA, float* __restrict__ CBT) {
  __shared__ float e[NR * 64];
  const int bx = blockIdx.x;
  const int tid = threadIdx.x;

  if (bx < 576) {                       // ---- tfeat partial (k-chunk 128)
    const int j = (bx & 3) * 256 + tid;
    const int kc = bx >> 2;             // [0,144)
    const int kbase = kc * 128;
    float acc[NB] = {};
    for (int kk = 0; kk < 128; ++kk) {
      const int k = kbase + kk;
      const float w = W_ct[(size_t)k * NTF + j];
      const float* x = (k < 9216) ? (As + k) : (Bs + (k - 9216));
#pragma unroll
      for (int b = 0; b < NB; ++b) acc[b] = fmaf(x[b * 9216], w, acc[b]);
    }
    const int rep = kc & 3;
#pragma unroll
    for (int b = 0; b < NB; ++b)
      atomicAdd(fAcc + (size_t)(rep * NB + b) * NFUSED + j, acc[b]);
  } else if (bx < 640) {                // ---- pfeat partial (k-chunk 128)
    const int t = bx - 576;
    const int j = (t & 1) * 256 + tid;
    const int kc = t >> 1;              // [0,32)
    const int kbase = kc * 128;
    float acc[NB] = {};
    for (int kk = 0; kk < 128; ++kk) {
      const int k = kbase + kk;
      const float w = W_cp[(size_t)k * NPF + j];
#pragma unroll
      for (int b = 0; b < NB; ++b) acc[b] = fmaf(prompt[b * KP + k], w, acc[b]);
    }
    const int rep = kc & 3;
#pragma unroll
    for (int b = 0; b < NB; ++b)
      atomicAdd(fAcc + (size_t)(rep * NB + b) * NFUSED + NTF + j, acc[b]);
  } else if (bx < 704) {                // ---- L_A / L_B (split-K 2 halves)
    const int t = bx - 640;
    const bool isA = t < 32;
    const int tt = isA ? t : t - 32;
    const int dc = tt & 15;
    const int kh = tt >> 4;             // 0 or 1
    const float* W = (isA ? W_A : W_B) + (size_t)(NFUSED + kh * 128) * ND;
    float* pL = (isA ? pLA : pLB) + (size_t)kh * NL * ND;
    const int d = dc * 256 + tid;
    float acc[NL] = {};
    for (int kk = 0; kk < 128; ++kk) {
      const float w = W[(size_t)kk * ND + d];
      const float* el = E_layer + kh * 128 + kk;
#pragma unroll
      for (int l = 0; l < NL; ++l) acc[l] = fmaf(el[l * 256], w, acc[l]);
    }
#pragma unroll
    for (int l = 0; l < NL; ++l) pL[(size_t)l * ND + d] = acc[l];
  } else {                              // ---- C_A / C_BT
    const int t = bx - 704;
    const bool isA = t < 16;
    const int tt = isA ? t : t - 16;
    const float* W = (isA ? W_A : W_B) + (size_t)(NFUSED + 256) * ND;
    for (int i = tid; i < NR * 64; i += 256) e[i] = E_chunk[i];
    __syncthreads();
    const int d = tt * 256 + tid;
    float w[64];
#pragma unroll
    for (int k = 0; k < 64; ++k) w[k] = W[(size_t)k * ND + d];
    for (int r = 0; r < NR; ++r) {
      float s = 0.f;
#pragma unroll
      for (int k = 0; k < 64; ++k) s = fmaf(e[r * 64 + k], w[k], s);
      if (isA) CA[(size_t)r * ND + d] = s;
      else     CBT[(size_t)d * NR + r] = s;
    }
  }
}

// =====================================================================
// K3: F partials + gate — 392 blocks. fused rebuilt from the 4-replica
// accumulator (4 adds + bias + relu per element).
//   [0,192)   F_A partial (dc = t&15, kc = t>>4)
//   [192,384) F_B partial
//   [384,392) gate, one batch per block
// =====================================================================
__global__ __launch_bounds__(256) void k_dep(
    const float* __restrict__ fAcc,
    const float* __restrict__ b_ct, const float* __restrict__ b_cp,
    const float* __restrict__ W_A, const float* __restrict__ W_B,
    const float* __restrict__ W_pc, const float* __restrict__ b_pc,
    float* __restrict__ pFA, float* __restrict__ pFB,
    float* __restrict__ gate_ws, float* __restrict__ gate_out) {
  __shared__ float sm[1664];
  const int bx = blockIdx.x;
  const int tid = threadIdx.x;

  if (bx < 384) {                       // ---- F partial
    const bool isA = bx < 192;
    const int t = isA ? bx : bx - 192;
    const float* W = isA ? W_A : W_B;
    float* part = isA ? pFA : pFB;
    const int dc = t & 15;
    const int kc = t >> 4;
    const int kbase = kc * 128;

    // stage fused slice [8][128] with replica-sum + bias + relu
    for (int i = tid; i < 1024; i += 256) {
      const int b = i >> 7, kk = i & 127;
      const int k = kbase + kk;
      float v = (k < NTF) ? b_ct[k] : b_cp[k - NTF];
#pragma unroll
      for (int rep = 0; rep < 4; ++rep)
        v += fAcc[(size_t)(rep * NB + b) * NFUSED + k];
      sm[i] = fmaxf(v, 0.f);
    }
    __syncthreads();

    const int d = dc * 256 + tid;
    float acc[NB] = {};
    for (int kk = 0; kk < 128; ++kk) {
      const float w = W[(size_t)(kbase + kk) * ND + d];
#pragma unroll
      for (int b = 0; b < NB; ++b) acc[b] = fmaf(sm[b * 128 + kk], w, acc[b]);
    }
#pragma unroll
    for (int b = 0; b < NB; ++b)
      part[(size_t)(kc * NB + b) * ND + d] = acc[b];
  } else {                              // ---- gate for batch b
    const int b = bx - 384;
    for (int j = tid; j < NFUSED; j += 256) {
      float v = (j < NTF) ? b_ct[j] : b_cp[j - NTF];
#pragma unroll
      for (int rep = 0; rep < 4; ++rep)
        v += fAcc[(size_t)(rep * NB + b) * NFUSED + j];
      sm[j] = fmaxf(v, 0.f);
    }
    __syncthreads();
    float acc[NL] = {};
    for (int j = tid; j < NFUSED; j += 256) {
      const float f = sm[j];
#pragma unroll
      for (int l = 0; l < NL; ++l) acc[l] = fmaf(f, W_pc[j * NL + l], acc[l]);
    }
#pragma unroll
    for (int off = 32; off > 0; off >>= 1)
#pragma unroll
      for (int l = 0; l < NL; ++l) acc[l] += __shfl_down(acc[l], off);
    const int wave = tid >> 6, lane = tid & 63;
    if (lane == 0)
#pragma unroll
      for (int l = 0; l < NL; ++l) sm[NFUSED + wave * NL + l] = acc[l];
    __syncthreads();
    if (tid < NL) {
      float s = b_pc[tid];
#pragma unroll
      for (int w = 0; w < 4; ++w) s += sm[NFUSED + w * NL + tid];
      const float g = s > 0.f ? 1.f : 0.f;
      gate_ws[b * NL + tid] = g;
      gate_out[b * NL + tid] = g;
    }
  }
}

// =====================================================================
// K4: writers (F-reduce + L-reduce folded in) — 3072 blocks (R3 verbatim)
// =====================================================================
__global__ __launch_bounds__(256) void k_out(
    const float* __restrict__ pFA, const float* __restrict__ pFB,
    const float* __restrict__ b_A, const float* __restrict__ b_B,
    const float* __restrict__ pLA, const float* __restrict__ pLB,
    const float* __restrict__ CA, const float* __restrict__ CBT,
    const float* __restrict__ gate,
    float* __restrict__ outA, float* __restrict__ outB) {
  __shared__ float sbase[512];
  const int bx = blockIdx.x;
  const int tid = threadIdx.x;
  if (bx < 1536) {                      // ---- A writer
    const int bl = bx >> 3;
    const int rest = bx & 7;
    const int b = bl / NL, l = bl % NL;
    const int d = (rest >> 1) * 1024 + tid * 4;
    const int r0 = (rest & 1) * 32;
    const float g = gate[bl];
    v4f base = *(const v4f*)(b_A + d);
#pragma unroll
    for (int kc = 0; kc < FKC; ++kc)
      base += *(const v4f*)(pFA + (size_t)(kc * NB + b) * ND + d);
    base += *(const v4f*)(pLA + (size_t)l * ND + d);
    base += *(const v4f*)(pLA + (size_t)(NL + l) * ND + d);
    float* outp = outA + ((size_t)bl * NR + r0) * ND + d;
#pragma unroll 4
    for (int r = 0; r < 32; ++r) {
      const v4f c = *(const v4f*)(CA + (size_t)(r0 + r) * ND + d);
      const v4f v = (base + c) * g;
      __builtin_nontemporal_store(v, (v4f*)outp);
      outp += ND;
    }
  } else {                              // ---- B writer
    const int t = bx - 1536;
    const int bl = t >> 3;
    const int b = bl / NL, l = bl % NL;
    const int dbase = (t & 7) * 512;
    for (int dd = tid; dd < 512; dd += 256) {
      const int d = dbase + dd;
      float s = b_B[d] + pLB[(size_t)l * ND + d] + pLB[(size_t)(NL + l) * ND + d];
#pragma unroll
      for (int kc = 0; kc < FKC; ++kc)
        s += pFB[(size_t)(kc * NB + b) * ND + d];
      sbase[dd] = s;
    }
    __syncthreads();
    const int dd16 = tid >> 4;
    const int r4 = (tid & 15) * 4;
#pragma unroll 4
    for (int i = 0; i < 32; ++i) {
      const int dloc = i * 16 + dd16;
      const int d = dbase + dloc;
      const v4f c = *(const v4f*)(CBT + (size_t)d * NR + r4);
      const v4f v = c + sbase[dloc];
      __builtin_nontemporal_store(v, (v4f*)(outB + ((size_t)bl * ND + d) * NR + r4));
    }
  }
}

extern "C" void kernel_launch(void* const* d_in, const int* in_sizes, int n_in,
                              void* d_out, int out_size, void* d_ws, size_t ws_size,
                              hipStream_t stream) {
  const float* A_small   = (const float*)d_in[0];
  const float* B_small   = (const float*)d_in[1];
  const float* prompt    = (const float*)d_in[2];
  const float* W_ct      = (const float*)d_in[3];
  const float* b_ct      = (const float*)d_in[4];
  const float* W_cp      = (const float*)d_in[5];
  const float* b_cp      = (const float*)d_in[6];
  const float* W_pc      = (const float*)d_in[7];
  const float* b_pc      = (const float*)d_in[8];
  const float* E_layer   = (const float*)d_in[9];
  const float* E_chunk   = (const float*)d_in[10];
  const float* W_A       = (const float*)d_in[11];
  const float* b_A       = (const float*)d_in[12];
  const float* W_B       = (const float*)d_in[13];
  const float* b_B       = (const float*)d_in[14];

  float* ws    = (float*)d_ws;
  float* fAcc  = ws + WS_FACC;
  float* gatew = ws + WS_GATE;
  float* pLA   = ws + WS_PLA;
  float* pLB   = ws + WS_PLB;
  float* CA    = ws + WS_CA;
  float* CBT   = ws + WS_CBT;
  float* pFA   = ws + WS_PFA;
  float* pFB   = ws + WS_PFB;

  float* outA = (float*)d_out;                       // [192,64,4096]
  float* outB = outA + (size_t)192 * NR * ND;        // [192,4096,64]
  float* outG = outB + (size_t)192 * ND * NR;        // [192]

  // zero the 4-replica fused accumulator (needed fresh every call)
  hipMemsetAsync(fAcc, 0, (size_t)4 * NB * NFUSED * sizeof(float), stream);

  k_indep<<<736, 256, 0, stream>>>(A_small, B_small, W_ct, prompt, W_cp,
                                   E_layer, E_chunk, W_A, W_B,
                                   fAcc, pLA, pLB, CA, CBT);
  k_dep<<<392, 256, 0, stream>>>(fAcc, b_ct, b_cp, W_A, W_B,
                                 W_pc, b_pc, pFA, pFB, gatew, outG);
  k_out<<<3072, 256, 0, stream>>>(pFA, pFB, b_A, b_B, pLA, pLB, CA, CBT,
                                  gatew, outA, outB);
}